// Round 1
// baseline (203.422 us; speedup 1.0000x reference)
//
#include <hip/hip_runtime.h>
#include <hip/hip_bf16.h>
#include <math.h>

typedef unsigned short u16;
typedef __attribute__((ext_vector_type(4))) float f32x4;
typedef __attribute__((ext_vector_type(8))) __bf16 bf16x8;

// ---------------------------------------------------------------- fp32 -> bf16
__device__ __forceinline__ u16 f2bf(float x) {
    unsigned u = __float_as_uint(x);
    u += 0x7fffu + ((u >> 16) & 1u);   // round-to-nearest-even
    return (u16)(u >> 16);
}
__device__ __forceinline__ unsigned pk(float lo, float hi) {
    return (unsigned)f2bf(lo) | ((unsigned)f2bf(hi) << 16);
}

__global__ void cvt_bf16(const float* __restrict__ s, u16* __restrict__ d, int n) {
    int i = (blockIdx.x * blockDim.x + threadIdx.x) * 8;
    if (i >= n) return;
    float4 v0 = *(const float4*)(s + i);
    float4 v1 = *(const float4*)(s + i + 4);
    uint4 o;
    o.x = pk(v0.x, v0.y); o.y = pk(v0.z, v0.w);
    o.z = pk(v1.x, v1.y); o.w = pk(v1.z, v1.w);
    *(uint4*)(d + i) = o;
}

// ---------------------------------------------------------------- GEMM + max
#define GLB_AS __attribute__((address_space(1)))
#define LDS_AS __attribute__((address_space(3)))

__device__ __forceinline__ void gload_lds16(const void* g, void* l) {
    __builtin_amdgcn_global_load_lds((const GLB_AS void*)g, (LDS_AS void*)l, 16, 0, 0);
}

// A: F bf16 [1024 x 512], B: T bf16 [32768 x 512] (row-major, K contiguous)
// sim[i*1024 + j] = max_{q<32} dot(A[i], B[j*32+q]) / temp
__global__ __launch_bounds__(256, 2)
void gemm_max(const u16* __restrict__ A, const u16* __restrict__ B,
              const float* __restrict__ temp_ptr, float* __restrict__ sim) {
    __shared__ __align__(16) u16 lA[128 * 32];
    __shared__ __align__(16) u16 lB[128 * 32];
    const int bn = blockIdx.x;      // 0..255 (N tiles of 128 = 4 j's)
    const int bm = blockIdx.y;      // 0..7   (M tiles of 128)
    const int tid  = threadIdx.x;
    const int wave = tid >> 6;      // 0..3
    const int lane = tid & 63;
    const int wm = wave >> 1;       // 0..1
    const int wn = wave & 1;        // 0..1

    f32x4 acc[4][4] = {};

    // staging: wave w covers rows [w*16, w*16+16) and [64+w*16, ...)
    const int rA = lane >> 2;            // 0..15 row within 16-row group
    const int kc = (lane & 3) << 3;      // 0,8,16,24 (elems)
    const u16* gA = A + (size_t)(bm * 128 + wave * 16 + rA) * 512 + kc;
    const u16* gB = B + (size_t)(bn * 128 + wave * 16 + rA) * 512 + kc;
    u16* dA = lA + wave * 512;           // byte offset wave*1024
    u16* dB = lB + wave * 512;

    // fragment addressing (both A and B operands): m/n = lane&15, k = (lane>>4)*8+j
    const int frow = lane & 15;
    const int fko  = (lane >> 4) << 3;

    for (int k0 = 0; k0 < 512; k0 += 32) {
        gload_lds16(gA + k0,            dA);
        gload_lds16(gA + k0 + 64 * 512, dA + 2048);
        gload_lds16(gB + k0,            dB);
        gload_lds16(gB + k0 + 64 * 512, dB + 2048);
        __syncthreads();   // compiler emits s_waitcnt vmcnt(0) before barrier

        bf16x8 af[4], bf[4];
#pragma unroll
        for (int t = 0; t < 4; ++t) {
            af[t] = *(const bf16x8*)&lA[(wm * 64 + t * 16 + frow) * 32 + fko];
            bf[t] = *(const bf16x8*)&lB[(wn * 64 + t * 16 + frow) * 32 + fko];
        }
#pragma unroll
        for (int mt = 0; mt < 4; ++mt)
#pragma unroll
            for (int nt = 0; nt < 4; ++nt)
                acc[mt][nt] = __builtin_amdgcn_mfma_f32_16x16x32_bf16(
                    af[mt], bf[nt], acc[mt][nt], 0, 0, 0);
        __syncthreads();
    }

    // epilogue: C row = bm*128 + wm*64 + mt*16 + (lane>>4)*4 + rr
    //           C col = bn*128 + wn*64 + nt*16 + (lane&15)
    // max over 32 consecutive cols = one j; wave spans 2 j's (nt{0,1} / nt{2,3})
    const float tempv = *temp_ptr;
    const int quad = lane >> 4;
    const int jb = (bn * 128 + wn * 64) >> 5;   // first j of this wave
#pragma unroll
    for (int mt = 0; mt < 4; ++mt) {
#pragma unroll
        for (int rr = 0; rr < 4; ++rr) {
            float v0 = fmaxf(acc[mt][0][rr], acc[mt][1][rr]);
            float v1 = fmaxf(acc[mt][2][rr], acc[mt][3][rr]);
#pragma unroll
            for (int off = 1; off < 16; off <<= 1) {
                v0 = fmaxf(v0, __shfl_xor(v0, off));
                v1 = fmaxf(v1, __shfl_xor(v1, off));
            }
            if ((lane & 15) == 0) {
                const int row = bm * 128 + wm * 64 + mt * 16 + quad * 4 + rr;
                sim[row * 1024 + jb]     = v0 / tempv;
                sim[row * 1024 + jb + 1] = v1 / tempv;
            }
        }
    }
}

// ---------------------------------------------------------------- per-row loss
// one block per row i: loss_std_i + 0.5*hard_i, atomic-added (scaled 1/1024)
__global__ __launch_bounds__(256)
void row_loss(const float* __restrict__ sim, float* __restrict__ out) {
    __shared__ float row[1024];
    __shared__ float srt[1024];
    __shared__ float red[8];
    const int i = blockIdx.x;
    const int tid = threadIdx.x;
    const int lane = tid & 63;
    const int wv = tid >> 6;

    for (int t = tid; t < 1024; t += 256) row[t] = sim[i * 1024 + t];
    __syncthreads();
    const float pos = row[i];

    // ---- full-row logsumexp (includes diagonal) ----
    float m = -INFINITY;
    for (int t = tid; t < 1024; t += 256) m = fmaxf(m, row[t]);
    for (int off = 1; off < 64; off <<= 1) m = fmaxf(m, __shfl_xor(m, off));
    if (lane == 0) red[wv] = m;
    __syncthreads();
    m = fmaxf(fmaxf(red[0], red[1]), fmaxf(red[2], red[3]));
    __syncthreads();
    float s = 0.f;
    for (int t = tid; t < 1024; t += 256) s += __expf(row[t] - m);
    for (int off = 1; off < 64; off <<= 1) s += __shfl_xor(s, off);
    if (lane == 0) red[wv] = s;
    __syncthreads();
    const float loss_std = m + __logf(red[0] + red[1] + red[2] + red[3]) - pos;
    __syncthreads();

    // ---- bitonic sort (descending) of diag-masked row ----
    for (int t = tid; t < 1024; t += 256) srt[t] = (t == i) ? -INFINITY : row[t];
    for (int kk = 2; kk <= 1024; kk <<= 1) {
        for (int j = kk >> 1; j > 0; j >>= 1) {
            __syncthreads();
            for (int x = tid; x < 1024; x += 256) {
                const int p = x ^ j;
                if (p > x) {
                    const float a = srt[x], b = srt[p];
                    const bool desc = ((x & kk) == 0);
                    if (desc ? (a < b) : (a > b)) { srt[x] = b; srt[p] = a; }
                }
            }
        }
    }
    __syncthreads();

    // ---- lse over {pos} U top-512 ----
    const float mh = fmaxf(pos, srt[0]);
    float sh = 0.f;
    for (int t = tid; t < 512; t += 256) sh += __expf(srt[t] - mh);
    for (int off = 1; off < 64; off <<= 1) sh += __shfl_xor(sh, off);
    if (lane == 0) red[4 + wv] = sh;
    __syncthreads();
    if (tid == 0) {
        const float st = red[4] + red[5] + red[6] + red[7] + __expf(pos - mh);
        const float hard = mh + __logf(st) - pos;
        atomicAdd(out, (loss_std + 0.5f * hard) * (1.0f / 1024.0f));
    }
}

// ---------------------------------------------------------------- launch
extern "C" void kernel_launch(void* const* d_in, const int* in_sizes, int n_in,
                              void* d_out, int out_size, void* d_ws, size_t ws_size,
                              hipStream_t stream) {
    const float* F    = (const float*)d_in[0];   // 1024*512
    const float* T    = (const float*)d_in[1];   // 1024*32*512
    const float* temp = (const float*)d_in[2];   // scalar
    float* out = (float*)d_out;

    char* ws = (char*)d_ws;
    u16*  Fb  = (u16*)ws;                                   // 1 MB
    u16*  Tb  = (u16*)(ws + (1u << 20));                    // 32 MB
    float* sim = (float*)(ws + (1u << 20) + (32u << 20));   // 4 MB

    hipMemsetAsync(d_out, 0, sizeof(float), stream);

    cvt_bf16<<<256, 256, 0, stream>>>(F, Fb, 1024 * 512);
    cvt_bf16<<<8192, 256, 0, stream>>>(T, Tb, 32768 * 512);

    dim3 grid(256, 8);
    gemm_max<<<grid, 256, 0, stream>>>(Fb, Tb, temp, sim);

    row_loss<<<1024, 256, 0, stream>>>(sim, out);
}

// Round 2
// 170.807 us; speedup vs baseline: 1.1909x; 1.1909x over previous
//
#include <hip/hip_runtime.h>
#include <hip/hip_bf16.h>
#include <math.h>

typedef unsigned short u16;
typedef unsigned int u32;
typedef __attribute__((ext_vector_type(4))) float f32x4;
typedef __attribute__((ext_vector_type(8))) __bf16 bf16x8;

// ---------------------------------------------------------------- fp32 -> bf16
__device__ __forceinline__ u16 f2bf(float x) {
    unsigned u = __float_as_uint(x);
    u += 0x7fffu + ((u >> 16) & 1u);   // round-to-nearest-even
    return (u16)(u >> 16);
}
__device__ __forceinline__ unsigned pk(float lo, float hi) {
    return (unsigned)f2bf(lo) | ((unsigned)f2bf(hi) << 16);
}

__global__ void cvt_bf16(const float* __restrict__ s, u16* __restrict__ d, int n) {
    int i = (blockIdx.x * blockDim.x + threadIdx.x) * 8;
    if (i >= n) return;
    float4 v0 = *(const float4*)(s + i);
    float4 v1 = *(const float4*)(s + i + 4);
    uint4 o;
    o.x = pk(v0.x, v0.y); o.y = pk(v0.z, v0.w);
    o.z = pk(v1.x, v1.y); o.w = pk(v1.z, v1.w);
    *(uint4*)(d + i) = o;
}

// ---------------------------------------------------------------- GEMM + max
#define GLB_AS __attribute__((address_space(1)))
#define LDS_AS __attribute__((address_space(3)))

__device__ __forceinline__ void gload_lds16(const void* g, void* l) {
    __builtin_amdgcn_global_load_lds((const GLB_AS void*)g, (LDS_AS void*)l, 16, 0, 0);
}

// A: F bf16 [1024 x 512], B: T bf16 [32768 x 512] (row-major, K contiguous)
// sim[i*1024 + j] = max_{q<32} dot(A[i], B[j*32+q]) / temp
__global__ __launch_bounds__(256, 2)
void gemm_max(const u16* __restrict__ A, const u16* __restrict__ B,
              const float* __restrict__ temp_ptr, float* __restrict__ sim) {
    __shared__ __align__(16) u16 lA[128 * 32];
    __shared__ __align__(16) u16 lB[128 * 32];
    const int bn = blockIdx.x;      // 0..255 (N tiles of 128 = 4 j's)
    const int bm = blockIdx.y;      // 0..7   (M tiles of 128)
    const int tid  = threadIdx.x;
    const int wave = tid >> 6;      // 0..3
    const int lane = tid & 63;
    const int wm = wave >> 1;       // 0..1
    const int wn = wave & 1;        // 0..1

    f32x4 acc[4][4] = {};

    const int rA = lane >> 2;            // 0..15 row within 16-row group
    const int kc = (lane & 3) << 3;      // 0,8,16,24 (elems)
    const u16* gA = A + (size_t)(bm * 128 + wave * 16 + rA) * 512 + kc;
    const u16* gB = B + (size_t)(bn * 128 + wave * 16 + rA) * 512 + kc;
    u16* dA = lA + wave * 512;
    u16* dB = lB + wave * 512;

    const int frow = lane & 15;
    const int fko  = (lane >> 4) << 3;

    for (int k0 = 0; k0 < 512; k0 += 32) {
        gload_lds16(gA + k0,            dA);
        gload_lds16(gA + k0 + 64 * 512, dA + 2048);
        gload_lds16(gB + k0,            dB);
        gload_lds16(gB + k0 + 64 * 512, dB + 2048);
        __syncthreads();

        bf16x8 af[4], bf[4];
#pragma unroll
        for (int t = 0; t < 4; ++t) {
            af[t] = *(const bf16x8*)&lA[(wm * 64 + t * 16 + frow) * 32 + fko];
            bf[t] = *(const bf16x8*)&lB[(wn * 64 + t * 16 + frow) * 32 + fko];
        }
#pragma unroll
        for (int mt = 0; mt < 4; ++mt)
#pragma unroll
            for (int nt = 0; nt < 4; ++nt)
                acc[mt][nt] = __builtin_amdgcn_mfma_f32_16x16x32_bf16(
                    af[mt], bf[nt], acc[mt][nt], 0, 0, 0);
        __syncthreads();
    }

    const float tempv = *temp_ptr;
    const int quad = lane >> 4;
    const int jb = (bn * 128 + wn * 64) >> 5;
#pragma unroll
    for (int mt = 0; mt < 4; ++mt) {
#pragma unroll
        for (int rr = 0; rr < 4; ++rr) {
            float v0 = fmaxf(acc[mt][0][rr], acc[mt][1][rr]);
            float v1 = fmaxf(acc[mt][2][rr], acc[mt][3][rr]);
#pragma unroll
            for (int off = 1; off < 16; off <<= 1) {
                v0 = fmaxf(v0, __shfl_xor(v0, off));
                v1 = fmaxf(v1, __shfl_xor(v1, off));
            }
            if ((lane & 15) == 0) {
                const int row = bm * 128 + wm * 64 + mt * 16 + quad * 4 + rr;
                sim[row * 1024 + jb]     = v0 / tempv;
                sim[row * 1024 + jb + 1] = v1 / tempv;
            }
        }
    }
}

// ---------------------------------------------------------------- per-row loss
// ONE WAVE PER ROW, no __syncthreads. Row (1024 fp32) lives in 16 regs/lane.
// top-512 via 4-round byte radix-select on monotone uint keys (exact, tie-safe):
//   sum_top512 exp = sum_{key>t_key} exp(v) + (512 - cnt_gt)*exp(t)
__device__ __forceinline__ u32 f2key(float x) {
    u32 b = __float_as_uint(x);
    return (b & 0x80000000u) ? ~b : (b | 0x80000000u);
}
__device__ __forceinline__ float key2f(u32 k) {
    return __uint_as_float((k & 0x80000000u) ? (k & 0x7fffffffu) : ~k);
}

__global__ __launch_bounds__(256)
void row_loss(const float* __restrict__ sim, float* __restrict__ out) {
    __shared__ u32 hist[4 * 256];
    const int tid = threadIdx.x;
    const int lane = tid & 63;
    const int wv = tid >> 6;
    const int i = blockIdx.x * 4 + wv;          // row index
    u32* h = hist + wv * 256;

    // load row: slot t -> element (t>>2)*256 + lane*4 + (t&3)
    float v[16];
    const float4* rp = (const float4*)(sim + (size_t)i * 1024);
#pragma unroll
    for (int t = 0; t < 4; ++t) {
        float4 f = rp[t * 64 + lane];
        v[t * 4 + 0] = f.x; v[t * 4 + 1] = f.y; v[t * 4 + 2] = f.z; v[t * 4 + 3] = f.w;
    }
    u32 k[16];
#pragma unroll
    for (int t = 0; t < 16; ++t) k[t] = f2key(v[t]);

    const int dslot = ((i >> 8) << 2) | (i & 3);
    const int dlane = (i >> 2) & 63;
    if (dlane == lane) k[dslot] = 0u;           // mask diagonal (below any finite key)

    // full-row max + logsumexp (includes diagonal)
    float m = v[0];
#pragma unroll
    for (int t = 1; t < 16; ++t) m = fmaxf(m, v[t]);
#pragma unroll
    for (int off = 32; off > 0; off >>= 1) m = fmaxf(m, __shfl_xor(m, off));
    float s = 0.f;
#pragma unroll
    for (int t = 0; t < 16; ++t) s += __expf(v[t] - m);
#pragma unroll
    for (int off = 32; off > 0; off >>= 1) s += __shfl_xor(s, off);

    const float pos = __shfl(v[dslot], dlane);
    const float loss_std = m + __logf(s) - pos;

    // ---- radix select: value of the r-th largest key (r=512), tie-exact ----
    u32 prefix = 0;
    u32 r = 512;
#pragma unroll
    for (int d = 3; d >= 0; --d) {
        *(uint4*)(h + lane * 4) = uint4{0u, 0u, 0u, 0u};
        __builtin_amdgcn_wave_barrier();
#pragma unroll
        for (int t = 0; t < 16; ++t) {
            bool act = true;
            if (d < 3) act = ((k[t] >> (8 * (d + 1))) == prefix);
            if (act) atomicAdd(&h[(k[t] >> (8 * d)) & 255u], 1u);
        }
        __builtin_amdgcn_wave_barrier();
        uint4 c = *(const uint4*)(h + lane * 4);
        u32 local = c.x + c.y + c.z + c.w;
        // inclusive suffix-scan of per-lane sums
        u32 S = local;
#pragma unroll
        for (int off = 1; off < 64; off <<= 1) {
            u32 tmp = __shfl_down(S, off);
            if (lane + off < 64) S += tmp;
        }
        const u32 above = S - local;            // count of keys with byte >= (lane+1)*4
        const u32 cg3 = above + c.w;
        const u32 cg2 = cg3 + c.z;
        const u32 cg1 = cg2 + c.y;
        const u32 cg0 = cg1 + c.x;
        int q = -1;
        if      (cg3 >= r) q = 3;
        else if (cg2 >= r) q = 2;
        else if (cg1 >= r) q = 1;
        else if (cg0 >= r) q = 0;
        int cand = (q >= 0) ? (lane * 4 + q) : -1;
#pragma unroll
        for (int off = 32; off > 0; off >>= 1) cand = max(cand, __shfl_xor(cand, off));
        // owner lane computes new rank within chosen bucket
        const u32 cgq = (q == 3) ? cg3 : (q == 2) ? cg2 : (q == 1) ? cg1 : cg0;
        const u32 cq  = (q == 3) ? c.w : (q == 2) ? c.z : (q == 1) ? c.y : c.x;
        const u32 rp_local = r - (cgq - cq);    // r - cnt_ge(b*+1)
        r = __shfl(rp_local, cand >> 2);
        prefix = (prefix << 8) | (u32)cand;
    }

    const u32 t_key = prefix;
    const float tval = key2f(t_key);

    // exact top-512 logsumexp using threshold + tie count
    float se = 0.f;
    int cgt = 0;
#pragma unroll
    for (int t = 0; t < 16; ++t) {
        if (k[t] > t_key) { se += __expf(v[t] - m); ++cgt; }
    }
#pragma unroll
    for (int off = 32; off > 0; off >>= 1) se += __shfl_xor(se, off);
#pragma unroll
    for (int off = 32; off > 0; off >>= 1) cgt += __shfl_xor(cgt, off);

    const float sh = se + (float)(512 - cgt) * __expf(tval - m) + __expf(pos - m);
    const float hard = m + __logf(sh) - pos;

    if (lane == 0)
        atomicAdd(out, (loss_std + 0.5f * hard) * (1.0f / 1024.0f));
}

// ---------------------------------------------------------------- launch
extern "C" void kernel_launch(void* const* d_in, const int* in_sizes, int n_in,
                              void* d_out, int out_size, void* d_ws, size_t ws_size,
                              hipStream_t stream) {
    const float* F    = (const float*)d_in[0];   // 1024*512
    const float* T    = (const float*)d_in[1];   // 1024*32*512
    const float* temp = (const float*)d_in[2];   // scalar
    float* out = (float*)d_out;

    char* ws = (char*)d_ws;
    u16*  Fb  = (u16*)ws;                                   // 1 MB
    u16*  Tb  = (u16*)(ws + (1u << 20));                    // 32 MB
    float* sim = (float*)(ws + (1u << 20) + (32u << 20));   // 4 MB

    hipMemsetAsync(d_out, 0, sizeof(float), stream);

    cvt_bf16<<<256, 256, 0, stream>>>(F, Fb, 1024 * 512);
    cvt_bf16<<<8192, 256, 0, stream>>>(T, Tb, 32768 * 512);

    dim3 grid(256, 8);
    gemm_max<<<grid, 256, 0, stream>>>(Fb, Tb, temp, sim);

    row_loss<<<1024 / 4, 256, 0, stream>>>(sim, out);
}